// Round 8
// baseline (1127.850 us; speedup 1.0000x reference)
//
#include <hip/hip_runtime.h>
#include <hip/hip_bf16.h>

#define N_NODES 10000
#define N_EDGES 160000
#define FEAT_W 320
#define CHUNK 16

__device__ __forceinline__ float gelu_tanh(float x) {
    float x3 = x * x * x;
    float t = tanhf(0.7978845608028654f * (x + 0.044715f * x3));
    return 0.5f * x * (1.0f + t);
}

__device__ __forceinline__ float rl(float v, int k) {
    return __int_as_float(__builtin_amdgcn_readlane(__float_as_int(v), k));
}

// ---------------- Kernel 1: node transforms, 8 nodes/block ------------------
// feat_tbl / self_tbl rows: [0..128) = mul0 part, [128..320) = mul1 part as u*3+i
__global__ __launch_bounds__(256) void node_transform(
    const float* __restrict__ node_input,
    const float* __restrict__ Wa0, const float* __restrict__ Wa1,
    const float* __restrict__ Wb0, const float* __restrict__ Wb1,
    float* __restrict__ feat_tbl, float* __restrict__ self_tbl)
{
    __shared__ float x[8][FEAT_W];         // 10.24 KB
    const int node0 = blockIdx.x * 8;
    const int t = threadIdx.x;
    for (int q = t; q < 8 * FEAT_W / 4; q += 256)
        ((float4*)x)[q] = ((const float4*)(node_input + (size_t)node0 * FEAT_W))[q];
    __syncthreads();

    for (int g = 0; g < 3; ++g) {
        const int oidx = t + g * 256;
        if (oidx >= 640) break;
        const bool is_self = (oidx >= 320);
        const int idx = is_self ? oidx - 320 : oidx;
        float acc[8] = {0, 0, 0, 0, 0, 0, 0, 0};
        if (idx < 128) {
            const float* W = is_self ? Wb0 : Wa0;
            for (int v = 0; v < 128; ++v) {
                const float wv = W[v * 128 + idx];
#pragma unroll
                for (int n = 0; n < 8; ++n) acc[n] += x[n][v] * wv;
            }
#pragma unroll
            for (int n = 0; n < 8; ++n) acc[n] *= 0.08838834764831845f;  // 1/sqrt(128)
        } else {
            const int r = idx - 128, u = r / 3, i = r - 3 * u;
            const float* W = is_self ? Wb1 : Wa1;
            for (int v = 0; v < 64; ++v) {
                const float wv = W[v * 64 + u];
#pragma unroll
                for (int n = 0; n < 8; ++n) acc[n] += x[n][128 + v * 3 + i] * wv;
            }
#pragma unroll
            for (int n = 0; n < 8; ++n) acc[n] *= 0.125f;                // 1/sqrt(64)
        }
        float* outp = is_self ? self_tbl : feat_tbl;
#pragma unroll
        for (int n = 0; n < 8; ++n)
            outp[(size_t)(node0 + n) * FEAT_W + idx] = acc[n];
    }
}

// ---------------- Kernel 2: per-edge MLP -> h2 ------------------------------
__global__ __launch_bounds__(256) void mlp_kernel(
    const float* __restrict__ esa,   // (E,8)
    const float* __restrict__ M1,    // (8,64)
    const float* __restrict__ M2,    // (64,64)
    float* __restrict__ h2buf)       // (E,64)
{
    __shared__ float sh[4][64];
    const int wave = threadIdx.x >> 6;
    const int lane = threadIdx.x & 63;
    const int e = blockIdx.x * 4 + wave;   // N_EDGES % 4 == 0

    const float* er = esa + (size_t)e * 8;
    float h = 0.f;
#pragma unroll
    for (int k = 0; k < 8; ++k) h += er[k] * M1[k * 64 + lane];
    h = gelu_tanh(h * 0.35355339059327373f);   // 1/sqrt(8)
    sh[wave][lane] = h;
    __syncthreads();

    float h2 = 0.f;
    for (int v = 0; v < 64; ++v) h2 += sh[wave][v] * M2[v * 64 + lane];
    h2 = gelu_tanh(h2 * 0.125f);               // 1/sqrt(64)
    h2buf[(size_t)e * 64 + lane] = h2;
}

// ---------------- CSR build -------------------------------------------------
__global__ void count_kernel(const int* __restrict__ edge_dst, int* __restrict__ counts) {
    int e = blockIdx.x * 256 + threadIdx.x;
    if (e < N_EDGES) atomicAdd(&counts[edge_dst[e]], 1);
}

__global__ __launch_bounds__(1024) void scan_kernel(
    const int* __restrict__ counts, int* __restrict__ offsets, int* __restrict__ cursor)
{
    __shared__ int buf[1024];
    int base = 0;
    for (int c = 0; c < 10; ++c) {            // 10*1024 >= 10000
        int i = c * 1024 + threadIdx.x;
        int v = (i < N_NODES) ? counts[i] : 0;
        buf[threadIdx.x] = v;
        __syncthreads();
        for (int off = 1; off < 1024; off <<= 1) {
            int t = (threadIdx.x >= off) ? buf[threadIdx.x - off] : 0;
            __syncthreads();
            buf[threadIdx.x] += t;
            __syncthreads();
        }
        int excl = buf[threadIdx.x] - v;
        if (i < N_NODES) { offsets[i] = base + excl; cursor[i] = base + excl; }
        int tot = buf[1023];
        __syncthreads();
        base += tot;
    }
    if (threadIdx.x == 0) offsets[N_NODES] = base;
}

__global__ void fill_kernel(const int* __restrict__ edge_dst,
                            int* __restrict__ cursor, int* __restrict__ elist) {
    int e = blockIdx.x * 256 + threadIdx.x;
    if (e < N_EDGES) {
        int pos = atomicAdd(&cursor[edge_dst[e]], 1);
        elist[pos] = e;
    }
}

// ---------------- Kernel 3: fused gather: proj + TP + out-GEMM --------------
// 384 threads/block, one block per node. Thread t owns weight column u=t AND
// consumes its own projection results (no ws LDS roundtrip):
//   t in [0,128):   A: w0[t]   -> mid0a[t]            (1 acc)
//   t in [128,256): B: w1[t-128] -> mid1a[u'][0..2]   (3 accs)
//   t in [256,320): C: w2[t-256] -> mid1b[u'][0..2]   (3 accs)
//   t in [320,384): D: w3[t-320] -> mid0b[u']         (1 acc)
// h2 broadcast via v_readlane (no LDS). Feat prefetched to registers.
// z layout: [0,192) = z0 (mid0a | mid0b); [192+i*192+v) = z1[v][i] planes.
__global__ __launch_bounds__(384, 4) void gather_kernel(
    const int* __restrict__ offsets, const int* __restrict__ elist,
    const int* __restrict__ edge_src,
    const float* __restrict__ edge_attr,   // (E,4)
    const float* __restrict__ h2buf,       // (E,64)
    const float* __restrict__ feat_tbl,    // (N,320)
    const float* __restrict__ self_tbl,    // (N,320)
    const float* __restrict__ Wtp0,        // (64,128)
    const float* __restrict__ Wtp1,        // (64,128)
    const float* __restrict__ Wtp2,        // (64,64)
    const float* __restrict__ Wtp3,        // (64,64)
    const float* __restrict__ Wo0,         // (192,128)
    const float* __restrict__ Wo1,         // (192,64)
    float* __restrict__ out)               // (N,320)
{
    __shared__ float ys[CHUNK][4];         // 256 B
    __shared__ float z[768];               // 3 KB

    const int node = blockIdx.x;
    const int t = threadIdx.x;             // 0..383
    const int lane = t & 63;

    // weight column for this thread (wave-uniform branch selection)
    const float* wcol; int wstride;
    if (t < 128)      { wcol = Wtp0 + t;         wstride = 128; }
    else if (t < 256) { wcol = Wtp1 + (t - 128); wstride = 128; }
    else if (t < 320) { wcol = Wtp2 + (t - 256); wstride = 64;  }
    else              { wcol = Wtp3 + (t - 320); wstride = 64;  }

    // feat indices this thread needs (per edge): kind-dependent
    // A: feat[t]; B: feat[t-128]; C/D: feat[128+3u'+{0,1,2}]
    int f0;
    if (t < 128)      f0 = t;
    else if (t < 256) f0 = t - 128;
    else if (t < 320) f0 = 128 + 3 * (t - 256);
    else              f0 = 128 + 3 * (t - 320);

    float acc = 0.f, acc3a = 0.f, acc3b = 0.f, acc3c = 0.f;
    const int beg = offsets[node], end = offsets[node + 1];

    for (int cb = beg; cb < end; cb += CHUNK) {
        const int ne = min(CHUNK, end - cb);
        if (t < ne) {
            const int eidT = elist[cb + t];
            ((float4*)ys)[t] = ((const float4*)edge_attr)[eidT];
        }

        // ---- per-thread prefetch: h2 rows (coalesced, lane k = h2[e][k]) and feat ----
        float hv[CHUNK];
        float fv0[CHUNK], fv1[CHUNK], fv2[CHUNK];
#pragma unroll
        for (int e = 0; e < CHUNK; ++e) hv[e] = 0.f;
        for (int e = 0; e < ne; ++e) {
            const int eid = elist[cb + e];                       // uniform, L1-hot
            hv[e] = h2buf[(size_t)eid * 64 + lane];
            const int src = edge_src[eid];                       // uniform, L1-hot
            const float* fr = feat_tbl + (size_t)src * FEAT_W;
            fv0[e] = fr[f0];
            if (t >= 256) {                                      // kinds C, D need e1 xyz
                fv1[e] = fr[f0 + 1];
                fv2[e] = fr[f0 + 2];
            }
        }
        __syncthreads();   // ys visible

        // ---- projection: a[e] = h2[e] . wcol  (readlane broadcast, no LDS) ----
        float a[CHUNK];
#pragma unroll
        for (int e = 0; e < CHUNK; ++e) a[e] = 0.f;
#pragma unroll 16
        for (int k = 0; k < 64; ++k) {
            const float wv = wcol[k * wstride];
#pragma unroll
            for (int e = 0; e < CHUNK; ++e)
                a[e] += rl(hv[e], k) * wv;
        }

        // ---- tensor product accumulate (wave-uniform kind branches) ----
        if (t < 128) {                       // A: mid0a
            for (int e = 0; e < ne; ++e)
                acc += a[e] * fv0[e] * ys[e][0];
        } else if (t < 256) {                // B: mid1a (3 comps share w*e0)
            for (int e = 0; e < ne; ++e) {
                const float p = a[e] * fv0[e];
                acc3a += p * ys[e][1];
                acc3b += p * ys[e][2];
                acc3c += p * ys[e][3];
            }
        } else if (t < 320) {                // C: mid1b (w*y0 shared)
            for (int e = 0; e < ne; ++e) {
                const float p = a[e] * ys[e][0];
                acc3a += p * fv0[e];
                acc3b += p * fv1[e];
                acc3c += p * fv2[e];
            }
        } else {                             // D: mid0b (dot e1.y1)
            for (int e = 0; e < ne; ++e) {
                const float d = fv0[e] * ys[e][1] + fv1[e] * ys[e][2] + fv2[e] * ys[e][3];
                acc += a[e] * d;
            }
        }
        __syncthreads();   // before next chunk overwrites ys
    }

    // ---- write z (fold proj 1/8 and agg 1/sqrt(16)) ----
    const float sZ = 0.125f * 0.25f;
    if (t < 128) {
        z[t] = acc * sZ;                                   // z0 mul0 part
    } else if (t < 256) {
        const int u = t - 128;
        z[192 + 0 * 192 + u] = acc3a * sZ;                 // z1[v=u][i]
        z[192 + 1 * 192 + u] = acc3b * sZ;
        z[192 + 2 * 192 + u] = acc3c * sZ;
    } else if (t < 320) {
        const int u = t - 256;
        z[192 + 0 * 192 + 128 + u] = acc3a * sZ;           // z1[v=128+u][i]
        z[192 + 1 * 192 + 128 + u] = acc3b * sZ;
        z[192 + 2 * 192 + 128 + u] = acc3c * sZ;
    } else {
        z[128 + (t - 320)] = acc * sZ * 0.5773502691896258f;  // mid0b, 1/sqrt(3)
    }
    __syncthreads();

    // ---- output GEMM + rotation combine ----
    const float sA = 0.07216878364870323f;   // 1/sqrt(192)
    const float cR = 0.92387953251128674f;   // cos(pi/8)
    const float sR = 0.38268343236508978f;   // sin(pi/8)

    if (t < 128) {
        // out col t: sum_v z0[v] * Wo0[v*128+t], z0 = z[0..192) contiguous
        float conv = 0.f;
        const float4* z4 = (const float4*)z;
#pragma unroll 8
        for (int q = 0; q < 48; ++q) {
            const float4 zz = z4[q];
            conv += zz.x * Wo0[(4 * q + 0) * 128 + t];
            conv += zz.y * Wo0[(4 * q + 1) * 128 + t];
            conv += zz.z * Wo0[(4 * q + 2) * 128 + t];
            conv += zz.w * Wo0[(4 * q + 3) * 128 + t];
        }
        const float sv = self_tbl[(size_t)node * FEAT_W + t];
        out[(size_t)node * FEAT_W + t] = cR * sv + sR * conv * sA;
    } else if (t < 320) {
        const int idx = t - 128;
        const int i = idx >> 6, u = idx & 63;
        // conv1[u][i] = sum_v z1[v][i] * Wo1[v*64+u]; plane contiguous
        float conv = 0.f;
        const float4* z4 = (const float4*)(z + 192 + i * 192);
#pragma unroll 8
        for (int q = 0; q < 48; ++q) {
            const float4 zz = z4[q];
            conv += zz.x * Wo1[(4 * q + 0) * 64 + u];
            conv += zz.y * Wo1[(4 * q + 1) * 64 + u];
            conv += zz.z * Wo1[(4 * q + 2) * 64 + u];
            conv += zz.w * Wo1[(4 * q + 3) * 64 + u];
        }
        const int col = 128 + u * 3 + i;
        const float sv = self_tbl[(size_t)node * FEAT_W + col];
        out[(size_t)node * FEAT_W + col] = cR * sv + sR * conv * sA;
    }
}

extern "C" void kernel_launch(void* const* d_in, const int* in_sizes, int n_in,
                              void* d_out, int out_size, void* d_ws, size_t ws_size,
                              hipStream_t stream) {
    const float* node_input = (const float*)d_in[0];
    const float* edge_attr  = (const float*)d_in[1];
    const float* esa        = (const float*)d_in[2];
    const float* Wa0  = (const float*)d_in[3];
    const float* Wa1  = (const float*)d_in[4];
    const float* Wb0  = (const float*)d_in[5];
    const float* Wb1  = (const float*)d_in[6];
    const float* M1   = (const float*)d_in[7];
    const float* M2   = (const float*)d_in[8];
    const float* Wtp0 = (const float*)d_in[9];
    const float* Wtp1 = (const float*)d_in[10];
    const float* Wtp2 = (const float*)d_in[11];
    const float* Wtp3 = (const float*)d_in[12];
    const float* Wo0  = (const float*)d_in[13];
    const float* Wo1  = (const float*)d_in[14];
    const int* edge_src = (const int*)d_in[15];
    const int* edge_dst = (const int*)d_in[16];
    float* out = (float*)d_out;

    // ws usage: 16.64M floats + 0.34M ints ~= 68 MB (proven in R2-R7)
    float* feat_tbl = (float*)d_ws;                               // 10000*320
    float* self_tbl = feat_tbl + (size_t)N_NODES * FEAT_W;        // 10000*320
    float* h2buf    = self_tbl + (size_t)N_NODES * FEAT_W;        // 160000*64
    int*   counts   = (int*)(h2buf + (size_t)N_EDGES * 64);       // 10000
    int*   offsets  = counts + N_NODES;                           // 10001
    int*   cursor   = offsets + N_NODES + 1;                      // 10000
    int*   elist    = cursor + N_NODES;                           // 160000

    hipMemsetAsync(counts, 0, sizeof(int) * N_NODES, stream);

    node_transform<<<N_NODES / 8, 256, 0, stream>>>(node_input, Wa0, Wa1, Wb0, Wb1,
                                                    feat_tbl, self_tbl);
    mlp_kernel<<<N_EDGES / 4, 256, 0, stream>>>(esa, M1, M2, h2buf);
    count_kernel<<<N_EDGES / 256, 256, 0, stream>>>(edge_dst, counts);
    scan_kernel<<<1, 1024, 0, stream>>>(counts, offsets, cursor);
    fill_kernel<<<N_EDGES / 256, 256, 0, stream>>>(edge_dst, cursor, elist);
    gather_kernel<<<N_NODES, 384, 0, stream>>>(offsets, elist, edge_src,
                                               edge_attr, h2buf, feat_tbl, self_tbl,
                                               Wtp0, Wtp1, Wtp2, Wtp3, Wo0, Wo1, out);
}

// Round 9
// 990.473 us; speedup vs baseline: 1.1387x; 1.1387x over previous
//
#include <hip/hip_runtime.h>
#include <hip/hip_bf16.h>

#define N_NODES 10000
#define N_EDGES 160000
#define FEAT_W 320
#define CHUNK 16

__device__ __forceinline__ float gelu_tanh(float x) {
    float x3 = x * x * x;
    float t = tanhf(0.7978845608028654f * (x + 0.044715f * x3));
    return 0.5f * x * (1.0f + t);
}

// ---------------- Kernel 1: node transforms, 8 nodes/block ------------------
// feat_tbl / self_tbl rows: [0..128) = mul0 part, [128..320) = mul1 part as u*3+i
__global__ __launch_bounds__(256) void node_transform(
    const float* __restrict__ node_input,
    const float* __restrict__ Wa0, const float* __restrict__ Wa1,
    const float* __restrict__ Wb0, const float* __restrict__ Wb1,
    float* __restrict__ feat_tbl, float* __restrict__ self_tbl)
{
    __shared__ float x[8][FEAT_W];         // 10.24 KB
    const int node0 = blockIdx.x * 8;
    const int t = threadIdx.x;
    for (int q = t; q < 8 * FEAT_W / 4; q += 256)
        ((float4*)x)[q] = ((const float4*)(node_input + (size_t)node0 * FEAT_W))[q];
    __syncthreads();

    for (int g = 0; g < 3; ++g) {
        const int oidx = t + g * 256;
        if (oidx >= 640) break;
        const bool is_self = (oidx >= 320);
        const int idx = is_self ? oidx - 320 : oidx;
        float acc[8] = {0, 0, 0, 0, 0, 0, 0, 0};
        if (idx < 128) {
            const float* W = is_self ? Wb0 : Wa0;
            for (int v = 0; v < 128; ++v) {
                const float wv = W[v * 128 + idx];
#pragma unroll
                for (int n = 0; n < 8; ++n) acc[n] += x[n][v] * wv;
            }
#pragma unroll
            for (int n = 0; n < 8; ++n) acc[n] *= 0.08838834764831845f;  // 1/sqrt(128)
        } else {
            const int r = idx - 128, u = r / 3, i = r - 3 * u;
            const float* W = is_self ? Wb1 : Wa1;
            for (int v = 0; v < 64; ++v) {
                const float wv = W[v * 64 + u];
#pragma unroll
                for (int n = 0; n < 8; ++n) acc[n] += x[n][128 + v * 3 + i] * wv;
            }
#pragma unroll
            for (int n = 0; n < 8; ++n) acc[n] *= 0.125f;                // 1/sqrt(64)
        }
        float* outp = is_self ? self_tbl : feat_tbl;
#pragma unroll
        for (int n = 0; n < 8; ++n)
            outp[(size_t)(node0 + n) * FEAT_W + idx] = acc[n];
    }
}

// ---------------- Kernel 2: per-edge MLP -> h2 ------------------------------
__global__ __launch_bounds__(256) void mlp_kernel(
    const float* __restrict__ esa,   // (E,8)
    const float* __restrict__ M1,    // (8,64)
    const float* __restrict__ M2,    // (64,64)
    float* __restrict__ h2buf)       // (E,64)
{
    __shared__ float sh[4][64];
    const int wave = threadIdx.x >> 6;
    const int lane = threadIdx.x & 63;
    const int e = blockIdx.x * 4 + wave;   // N_EDGES % 4 == 0

    const float* er = esa + (size_t)e * 8;
    float h = 0.f;
#pragma unroll
    for (int k = 0; k < 8; ++k) h += er[k] * M1[k * 64 + lane];
    h = gelu_tanh(h * 0.35355339059327373f);   // 1/sqrt(8)
    sh[wave][lane] = h;
    __syncthreads();

    float h2 = 0.f;
    for (int v = 0; v < 64; ++v) h2 += sh[wave][v] * M2[v * 64 + lane];
    h2 = gelu_tanh(h2 * 0.125f);               // 1/sqrt(64)
    h2buf[(size_t)e * 64 + lane] = h2;
}

// ---------------- CSR build -------------------------------------------------
__global__ void count_kernel(const int* __restrict__ edge_dst, int* __restrict__ counts) {
    int e = blockIdx.x * 256 + threadIdx.x;
    if (e < N_EDGES) atomicAdd(&counts[edge_dst[e]], 1);
}

__global__ __launch_bounds__(1024) void scan_kernel(
    const int* __restrict__ counts, int* __restrict__ offsets, int* __restrict__ cursor)
{
    __shared__ int buf[1024];
    int base = 0;
    for (int c = 0; c < 10; ++c) {            // 10*1024 >= 10000
        int i = c * 1024 + threadIdx.x;
        int v = (i < N_NODES) ? counts[i] : 0;
        buf[threadIdx.x] = v;
        __syncthreads();
        for (int off = 1; off < 1024; off <<= 1) {
            int t = (threadIdx.x >= off) ? buf[threadIdx.x - off] : 0;
            __syncthreads();
            buf[threadIdx.x] += t;
            __syncthreads();
        }
        int excl = buf[threadIdx.x] - v;
        if (i < N_NODES) { offsets[i] = base + excl; cursor[i] = base + excl; }
        int tot = buf[1023];
        __syncthreads();
        base += tot;
    }
    if (threadIdx.x == 0) offsets[N_NODES] = base;
}

__global__ void fill_kernel(const int* __restrict__ edge_dst,
                            int* __restrict__ cursor, int* __restrict__ elist) {
    int e = blockIdx.x * 256 + threadIdx.x;
    if (e < N_EDGES) {
        int pos = atomicAdd(&cursor[edge_dst[e]], 1);
        elist[pos] = e;
    }
}

// ---------------- Kernel 3: fused gather: proj + TP + out-GEMM --------------
// 384 threads/block, one block per node. Thread t owns weight column u=t
// (64 regs, loaded once) AND consumes its own projection results:
//   t in [0,128):   A: w0[t]     -> mid0a[t]          (1 acc)
//   t in [128,256): B: w1[t-128] -> mid1a[u'][0..2]   (3 accs)
//   t in [256,320): C: w2[t-256] -> mid1b[u'][0..2]   (3 accs)
//   t in [320,384): D: w3[t-320] -> mid0b[u']         (1 acc)
// h2 tile in LDS, read as float4 broadcasts (ds_read_b128, 4x fewer LDS ops
// than R7's scalar reads). All register arrays indexed by static-bound loops.
// z layout: [0,192) = z0 (mid0a | mid0b); [192 + i*192 + v) = z1[v][i] planes.
__global__ __launch_bounds__(384, 2) void gather_kernel(
    const int* __restrict__ offsets, const int* __restrict__ elist,
    const int* __restrict__ edge_src,
    const float* __restrict__ edge_attr,   // (E,4)
    const float* __restrict__ h2buf,       // (E,64)
    const float* __restrict__ feat_tbl,    // (N,320)
    const float* __restrict__ self_tbl,    // (N,320)
    const float* __restrict__ Wtp0,        // (64,128)
    const float* __restrict__ Wtp1,        // (64,128)
    const float* __restrict__ Wtp2,        // (64,64)
    const float* __restrict__ Wtp3,        // (64,64)
    const float* __restrict__ Wo0,         // (192,128)
    const float* __restrict__ Wo1,         // (192,64)
    float* __restrict__ out)               // (N,320)
{
    __shared__ __align__(16) float h2s[CHUNK * 68];  // 4.25 KB, row stride 68
    __shared__ float ys[CHUNK][4];                   // 256 B
    __shared__ int   eids[CHUNK];
    __shared__ int   srcs[CHUNK];
    __shared__ float z[768];                         // 3 KB

    const int node = blockIdx.x;
    const int t = threadIdx.x;             // 0..383

    // ---- weight column into registers (once per kernel) ----
    const float* wcol; int wstride;
    if (t < 128)      { wcol = Wtp0 + t;         wstride = 128; }
    else if (t < 256) { wcol = Wtp1 + (t - 128); wstride = 128; }
    else if (t < 320) { wcol = Wtp2 + (t - 256); wstride = 64;  }
    else              { wcol = Wtp3 + (t - 320); wstride = 64;  }
    float wc[64];
#pragma unroll
    for (int k = 0; k < 64; ++k) wc[k] = wcol[k * wstride];

    // feat base index this thread needs per edge
    int f0;
    if (t < 128)      f0 = t;
    else if (t < 256) f0 = t - 128;
    else if (t < 320) f0 = 128 + 3 * (t - 256);
    else              f0 = 128 + 3 * (t - 320);

    float acc = 0.f, acc3a = 0.f, acc3b = 0.f, acc3c = 0.f;
    const int beg = offsets[node], end = offsets[node + 1];

    for (int cb = beg; cb < end; cb += CHUNK) {
        const int ne = min(CHUNK, end - cb);
        if (t < ne) eids[t] = elist[cb + t];
        __syncthreads();
        if (t < ne) {
            srcs[t] = edge_src[eids[t]];
            ((float4*)ys)[t] = ((const float4*)edge_attr)[eids[t]];
        }
        // stage h2 rows (coalesced; zero-fill e >= ne)
        for (int x = t; x < CHUNK * 64; x += 384) {
            int e = x >> 6, k = x & 63;
            h2s[e * 68 + k] = (e < ne) ? h2buf[(size_t)eids[e] * 64 + k] : 0.f;
        }
        __syncthreads();

        // ---- projection: a[e] = h2[e] . wc (b128 LDS broadcasts) ----
        float a[CHUNK];
#pragma unroll
        for (int e = 0; e < CHUNK; ++e) {
            a[e] = 0.f;
            if (e < ne) {                   // uniform branch, skips dead work
                const float4* hp = (const float4*)(h2s + e * 68);
                float s0 = 0.f, s1 = 0.f, s2 = 0.f, s3 = 0.f;
#pragma unroll
                for (int q = 0; q < 16; ++q) {
                    const float4 h = hp[q];
                    s0 += h.x * wc[4 * q + 0];
                    s1 += h.y * wc[4 * q + 1];
                    s2 += h.z * wc[4 * q + 2];
                    s3 += h.w * wc[4 * q + 3];
                }
                a[e] = (s0 + s1) + (s2 + s3);
            }
        }

        // ---- tensor product accumulate (wave-uniform kind branches) ----
        if (t < 128) {                       // A: mid0a
#pragma unroll
            for (int e = 0; e < CHUNK; ++e) {
                if (e < ne) {
                    const float* fr = feat_tbl + (size_t)srcs[e] * FEAT_W;
                    acc += a[e] * fr[f0] * ys[e][0];
                }
            }
        } else if (t < 256) {                // B: mid1a (3 comps share w*e0)
#pragma unroll
            for (int e = 0; e < CHUNK; ++e) {
                if (e < ne) {
                    const float* fr = feat_tbl + (size_t)srcs[e] * FEAT_W;
                    const float p = a[e] * fr[f0];
                    acc3a += p * ys[e][1];
                    acc3b += p * ys[e][2];
                    acc3c += p * ys[e][3];
                }
            }
        } else if (t < 320) {                // C: mid1b (w*y0 shared)
#pragma unroll
            for (int e = 0; e < CHUNK; ++e) {
                if (e < ne) {
                    const float* fr = feat_tbl + (size_t)srcs[e] * FEAT_W;
                    const float p = a[e] * ys[e][0];
                    acc3a += p * fr[f0];
                    acc3b += p * fr[f0 + 1];
                    acc3c += p * fr[f0 + 2];
                }
            }
        } else {                             // D: mid0b (dot e1.y1)
#pragma unroll
            for (int e = 0; e < CHUNK; ++e) {
                if (e < ne) {
                    const float* fr = feat_tbl + (size_t)srcs[e] * FEAT_W;
                    const float d = fr[f0] * ys[e][1] + fr[f0 + 1] * ys[e][2]
                                  + fr[f0 + 2] * ys[e][3];
                    acc += a[e] * d;
                }
            }
        }
        __syncthreads();   // before next chunk overwrites LDS
    }

    // ---- write z (fold proj 1/8 and agg 1/sqrt(16)) ----
    const float sZ = 0.125f * 0.25f;
    if (t < 128) {
        z[t] = acc * sZ;                                   // z0 mul0 part
    } else if (t < 256) {
        const int u = t - 128;
        z[192 + 0 * 192 + u] = acc3a * sZ;                 // z1[v=u][i]
        z[192 + 1 * 192 + u] = acc3b * sZ;
        z[192 + 2 * 192 + u] = acc3c * sZ;
    } else if (t < 320) {
        const int u = t - 256;
        z[192 + 0 * 192 + 128 + u] = acc3a * sZ;           // z1[v=128+u][i]
        z[192 + 1 * 192 + 128 + u] = acc3b * sZ;
        z[192 + 2 * 192 + 128 + u] = acc3c * sZ;
    } else {
        z[128 + (t - 320)] = acc * sZ * 0.5773502691896258f;  // mid0b, 1/sqrt(3)
    }
    __syncthreads();

    // ---- output GEMM + rotation combine ----
    const float sA = 0.07216878364870323f;   // 1/sqrt(192)
    const float cR = 0.92387953251128674f;   // cos(pi/8)
    const float sR = 0.38268343236508978f;   // sin(pi/8)

    if (t < 128) {
        // out col t: sum_v z0[v] * Wo0[v*128+t], z0 = z[0..192) contiguous
        float conv = 0.f;
        const float4* z4 = (const float4*)z;
#pragma unroll 8
        for (int q = 0; q < 48; ++q) {
            const float4 zz = z4[q];
            conv += zz.x * Wo0[(4 * q + 0) * 128 + t];
            conv += zz.y * Wo0[(4 * q + 1) * 128 + t];
            conv += zz.z * Wo0[(4 * q + 2) * 128 + t];
            conv += zz.w * Wo0[(4 * q + 3) * 128 + t];
        }
        const float sv = self_tbl[(size_t)node * FEAT_W + t];
        out[(size_t)node * FEAT_W + t] = cR * sv + sR * conv * sA;
    } else if (t < 320) {
        const int idx = t - 128;
        const int i = idx >> 6, u = idx & 63;
        // conv1[u][i] = sum_v z1[v][i] * Wo1[v*64+u]; plane contiguous
        float conv = 0.f;
        const float4* z4 = (const float4*)(z + 192 + i * 192);
#pragma unroll 8
        for (int q = 0; q < 48; ++q) {
            const float4 zz = z4[q];
            conv += zz.x * Wo1[(4 * q + 0) * 64 + u];
            conv += zz.y * Wo1[(4 * q + 1) * 64 + u];
            conv += zz.z * Wo1[(4 * q + 2) * 64 + u];
            conv += zz.w * Wo1[(4 * q + 3) * 64 + u];
        }
        const int col = 128 + u * 3 + i;
        const float sv = self_tbl[(size_t)node * FEAT_W + col];
        out[(size_t)node * FEAT_W + col] = cR * sv + sR * conv * sA;
    }
}

extern "C" void kernel_launch(void* const* d_in, const int* in_sizes, int n_in,
                              void* d_out, int out_size, void* d_ws, size_t ws_size,
                              hipStream_t stream) {
    const float* node_input = (const float*)d_in[0];
    const float* edge_attr  = (const float*)d_in[1];
    const float* esa        = (const float*)d_in[2];
    const float* Wa0  = (const float*)d_in[3];
    const float* Wa1  = (const float*)d_in[4];
    const float* Wb0  = (const float*)d_in[5];
    const float* Wb1  = (const float*)d_in[6];
    const float* M1   = (const float*)d_in[7];
    const float* M2   = (const float*)d_in[8];
    const float* Wtp0 = (const float*)d_in[9];
    const float* Wtp1 = (const float*)d_in[10];
    const float* Wtp2 = (const float*)d_in[11];
    const float* Wtp3 = (const float*)d_in[12];
    const float* Wo0  = (const float*)d_in[13];
    const float* Wo1  = (const float*)d_in[14];
    const int* edge_src = (const int*)d_in[15];
    const int* edge_dst = (const int*)d_in[16];
    float* out = (float*)d_out;

    // ws usage: 16.64M floats + 0.34M ints ~= 68 MB (proven in R2-R8)
    float* feat_tbl = (float*)d_ws;                               // 10000*320
    float* self_tbl = feat_tbl + (size_t)N_NODES * FEAT_W;        // 10000*320
    float* h2buf    = self_tbl + (size_t)N_NODES * FEAT_W;        // 160000*64
    int*   counts   = (int*)(h2buf + (size_t)N_EDGES * 64);       // 10000
    int*   offsets  = counts + N_NODES;                           // 10001
    int*   cursor   = offsets + N_NODES + 1;                      // 10000
    int*   elist    = cursor + N_NODES;                           // 160000

    hipMemsetAsync(counts, 0, sizeof(int) * N_NODES, stream);

    node_transform<<<N_NODES / 8, 256, 0, stream>>>(node_input, Wa0, Wa1, Wb0, Wb1,
                                                    feat_tbl, self_tbl);
    mlp_kernel<<<N_EDGES / 4, 256, 0, stream>>>(esa, M1, M2, h2buf);
    count_kernel<<<N_EDGES / 256, 256, 0, stream>>>(edge_dst, counts);
    scan_kernel<<<1, 1024, 0, stream>>>(counts, offsets, cursor);
    fill_kernel<<<N_EDGES / 256, 256, 0, stream>>>(edge_dst, cursor, elist);
    gather_kernel<<<N_NODES, 384, 0, stream>>>(offsets, elist, edge_src,
                                               edge_attr, h2buf, feat_tbl, self_tbl,
                                               Wtp0, Wtp1, Wtp2, Wtp3, Wo0, Wo1, out);
}